// Round 14
// baseline (200.384 us; speedup 1.0000x reference)
//
#include <hip/hip_runtime.h>
#include <math.h>

#define N 4096
#define NB 128         // bands per column
#define BANDSZ 32      // rows per band
#define KB 8           // slots per (band, col) cell
#define MAXDEG 128
#define NEG_SLOPE 0.2f
#define LN_EPS 1e-5f

typedef float vfloat4 __attribute__((ext_vector_type(4)));  // native vec for nontemporal builtins

__device__ __forceinline__ float wave_reduce_sum(float v) {
    #pragma unroll
    for (int m = 32; m >= 1; m >>= 1) v += __shfl_xor(v, m, 64);
    return v;
}
__device__ __forceinline__ float wave_reduce_max(float v) {
    #pragma unroll
    for (int m = 32; m >= 1; m >>= 1) v = fmaxf(v, __shfl_xor(v, m, 64));
    return v;
}

// row-vector (lane=col) times 64x64 row-major W via shfl broadcast.
__device__ __forceinline__ float transform_row(float hv, const float* __restrict__ W,
                                               int lane) {
    float tr = 0.f;
    #pragma unroll
    for (int k = 0; k < 64; ++k)
        tr += __shfl(hv, k, 64) * W[k * 64 + lane];
    return tr;
}

// softmax over neighbors (j0: first 64, j1: next 64, deg total) + weighted
// aggregation of hwin rows + bias. Indices/probs broadcast via shfl.
__device__ __forceinline__ float agg_core(int j0, int j1, int deg, float sd,
        const float* __restrict__ ssin, const float* __restrict__ hwin,
        const float* __restrict__ b, int lane) {
    float e0 = -1e30f, e1 = -1e30f;
    if (lane < deg)      { float v = ssin[j0] + sd; e0 = v > 0.f ? v : NEG_SLOPE * v; }
    if (lane + 64 < deg) { float v = ssin[j1] + sd; e1 = v > 0.f ? v : NEG_SLOPE * v; }
    float m = wave_reduce_max(fmaxf(e0, e1));
    float p0 = (lane < deg)      ? expf(e0 - m) : 0.f;
    float p1 = (lane + 64 < deg) ? expf(e1 - m) : 0.f;
    float Z = wave_reduce_sum(p0 + p1);
    float acc = 0.f;
    int d0 = min(deg, 64);
    #pragma unroll 4
    for (int n = 0; n < d0; ++n) {
        int   jj = __shfl(j0, n, 64);
        float p  = __shfl(p0, n, 64);
        acc += p * hwin[jj * 64 + lane];
    }
    for (int n = 64; n < deg; ++n) {
        int   jj = __shfl(j1, n - 64, 64);
        float p  = __shfl(p1, n - 64, 64);
        acc += p * hwin[jj * 64 + lane];
    }
    return acc / Z + b[lane];
}

// ---- dispatch 1: banded neighbor build + emb MLP + layer-0 transform.
// R12 geometry + layout (best so far) with NONTEMPORAL adjacency loads
// (pure stream, zero reuse — skip L2/L3 allocate) and nontemporal
// nbr2/cnt2 stores (write-combine, no read-for-ownership).
// Blocks [0,512): build — thread owns 4 consecutive cols x one 32-row band;
// cells in transposed (band*N+col) layout: thread's 4 cells = one 64B line.
// Blocks [512,1536): emb+tr0, one row per wave (keeps VGPR low — R8 lesson).
__global__ void __launch_bounds__(256) prep_kernel(
        const vfloat4* __restrict__ adj4, const int* __restrict__ timestep,
        const float* __restrict__ arr, const float* __restrict__ dep,
        const float* __restrict__ hard,
        const float* __restrict__ w1, const float* __restrict__ b1,
        const float* __restrict__ w2, const float* __restrict__ b2,
        const float* __restrict__ W0, const float* __restrict__ asrc,
        const float* __restrict__ adst,
        unsigned short* __restrict__ nbr2, unsigned char* __restrict__ cnt2,
        float* __restrict__ x, float* __restrict__ hwA,
        float* __restrict__ ssA, float* __restrict__ sdA,
        float* __restrict__ accum, int* __restrict__ done) {
    int wave = threadIdx.x >> 6;
    int lane = threadIdx.x & 63;
    if (blockIdx.x < 512) {
        int t    = blockIdx.x * 256 + threadIdx.x;   // 0..131071
        int cg   = t & 1023;                          // col group (4 cols)
        int band = t >> 10;                           // 0..127
        int i0   = cg * 4;
        int jbase = band * BANDSZ;
        int lc0 = 0, lc1 = 0, lc2 = 0, lc3 = 0;
        int b0  = (band * N + i0) * KB;               // 4 cells = one 64B line
        int b1  = b0 + KB;
        int b2_ = b0 + 2 * KB;
        int b3  = b0 + 3 * KB;
        #pragma unroll
        for (int batch = 0; batch < 4; ++batch) {
            vfloat4 a[8];
            #pragma unroll
            for (int u = 0; u < 8; ++u)
                a[u] = __builtin_nontemporal_load(
                           &adj4[(size_t)(jbase + batch * 8 + u) * 1024 + cg]);
            #pragma unroll
            for (int u = 0; u < 8; ++u) {
                int j = jbase + batch * 8 + u;
                if (a[u].x != 0.f || j == i0)     { if (lc0 < KB) __builtin_nontemporal_store((unsigned short)j, &nbr2[b0  + lc0]); ++lc0; }
                if (a[u].y != 0.f || j == i0 + 1) { if (lc1 < KB) __builtin_nontemporal_store((unsigned short)j, &nbr2[b1  + lc1]); ++lc1; }
                if (a[u].z != 0.f || j == i0 + 2) { if (lc2 < KB) __builtin_nontemporal_store((unsigned short)j, &nbr2[b2_ + lc2]); ++lc2; }
                if (a[u].w != 0.f || j == i0 + 3) { if (lc3 < KB) __builtin_nontemporal_store((unsigned short)j, &nbr2[b3  + lc3]); ++lc3; }
            }
        }
        int cb = band * N + i0;                       // 4 consecutive u8
        __builtin_nontemporal_store((unsigned char)(lc0 < KB ? lc0 : KB), &cnt2[cb]);
        __builtin_nontemporal_store((unsigned char)(lc1 < KB ? lc1 : KB), &cnt2[cb + 1]);
        __builtin_nontemporal_store((unsigned char)(lc2 < KB ? lc2 : KB), &cnt2[cb + 2]);
        __builtin_nontemporal_store((unsigned char)(lc3 < KB ? lc3 : KB), &cnt2[cb + 3]);
        if (blockIdx.x == 0 && threadIdx.x == 0) { *accum = 0.f; *done = 0; }
    } else {
        int row = (blockIdx.x - 512) * 4 + wave;      // one row per wave
        float ts = (float)(*timestep);
        float pr = (ts - arr[row]) / (dep[row] - arr[row]);
        float hd = hard[row];
        float t  = pr * w1[lane] + hd * w1[64 + lane] + b1[lane];
        float xv = b2[lane];
        #pragma unroll
        for (int k = 0; k < 64; ++k)
            xv += __shfl(t, k, 64) * w2[k * 64 + lane];
        x[row * 64 + lane] = xv;
        float tr = transform_row(xv, W0, lane);
        hwA[row * 64 + lane] = tr;
        float s1 = wave_reduce_sum(tr * asrc[lane]);
        float s2 = wave_reduce_sum(tr * adst[lane]);
        if (lane == 0) { ssA[row] = s1; sdA[row] = s2; }
    }
}

// ---- dispatch 2: compact banded lists (lane owns 2 bands of its row; wave
// prefix scan) + layer-0 aggregate + relu + layer-1 transform + scores.
__global__ void __launch_bounds__(256) compact_agg_tr(
        const unsigned short* __restrict__ nbr2, const unsigned char* __restrict__ cnt2,
        const float* __restrict__ hwin, const float* __restrict__ ssin,
        const float* __restrict__ sdin, const float* __restrict__ b,
        const float* __restrict__ W, const float* __restrict__ asrc,
        const float* __restrict__ adst,
        int* __restrict__ nbr_c, int* __restrict__ deg_arr,
        float* __restrict__ hwout, float* __restrict__ ssout,
        float* __restrict__ sdout) {
    __shared__ int lds[4][MAXDEG];
    int wave = threadIdx.x >> 6;
    int lane = threadIdx.x & 63;
    int i = blockIdx.x * 4 + wave;
    int cell0 = (2 * lane)     * N + i;   // transposed layout: band*N + col
    int cell1 = (2 * lane + 1) * N + i;
    int c0 = min((int)cnt2[cell0], KB);
    int c1 = min((int)cnt2[cell1], KB);
    int c  = c0 + c1;
    int inc = c;
    #pragma unroll
    for (int s = 1; s < 64; s <<= 1) {
        int t = __shfl_up(inc, s, 64);
        if (lane >= s) inc += t;
    }
    int off = inc - c;
    int deg = min(__shfl(inc, 63, 64), MAXDEG);
    {
        int base0 = cell0 * KB;
        int o = off;
        for (int k = 0; k < c0; ++k) { if (o < MAXDEG) lds[wave][o] = (int)nbr2[base0 + k]; ++o; }
        int base1 = cell1 * KB;
        for (int k = 0; k < c1; ++k) { if (o < MAXDEG) lds[wave][o] = (int)nbr2[base1 + k]; ++o; }
    }
    __syncthreads();
    int j0 = (lane < deg)      ? lds[wave][lane]      : 0;
    int j1 = (lane + 64 < deg) ? lds[wave][lane + 64] : 0;
    if (lane < deg)      nbr_c[i * MAXDEG + lane]      = j0;
    if (lane + 64 < deg) nbr_c[i * MAXDEG + lane + 64] = j1;
    if (lane == 0) deg_arr[i] = deg;
    float hv = fmaxf(agg_core(j0, j1, deg, sdin[i], ssin, hwin, b, lane), 0.f);
    float tr = transform_row(hv, W, lane);
    hwout[i * 64 + lane] = tr;
    float s1 = wave_reduce_sum(tr * asrc[lane]);
    float s2 = wave_reduce_sum(tr * adst[lane]);
    if (lane == 0) { ssout[i] = s1; sdout[i] = s2; }
}

// ---- dispatch 3: layer-1 aggregate + relu + layer-2 transform + scores.
__global__ void __launch_bounds__(256) agg_tr(
        const float* __restrict__ hwin, const float* __restrict__ ssin,
        const float* __restrict__ sdin, const int* __restrict__ nbr_c,
        const int* __restrict__ deg_arr, const float* __restrict__ b,
        const float* __restrict__ W, const float* __restrict__ asrc,
        const float* __restrict__ adst,
        float* __restrict__ hwout, float* __restrict__ ssout,
        float* __restrict__ sdout) {
    int wave = threadIdx.x >> 6;
    int lane = threadIdx.x & 63;
    int i = blockIdx.x * 4 + wave;
    int deg = deg_arr[i];
    int j0 = (lane < deg)      ? nbr_c[i * MAXDEG + lane]      : 0;
    int j1 = (lane + 64 < deg) ? nbr_c[i * MAXDEG + lane + 64] : 0;
    float hv = fmaxf(agg_core(j0, j1, deg, sdin[i], ssin, hwin, b, lane), 0.f);
    float tr = transform_row(hv, W, lane);
    hwout[i * 64 + lane] = tr;
    float s1 = wave_reduce_sum(tr * asrc[lane]);
    float s2 = wave_reduce_sum(tr * adst[lane]);
    if (lane == 0) { ssout[i] = s1; sdout[i] = s2; }
}

// ---- dispatch 4: layer-2 aggregate + residual + layernorm + val_w dot +
// block atomicAdd + last-block finish (accum/done pre-zeroed by dispatch 1).
__global__ void __launch_bounds__(256) agg_final_finish(
        const float* __restrict__ hwin, const float* __restrict__ ssin,
        const float* __restrict__ sdin, const int* __restrict__ nbr_c,
        const int* __restrict__ deg_arr, const float* __restrict__ b,
        const float* __restrict__ x, const float* __restrict__ vw,
        const float* __restrict__ vb,
        float* __restrict__ accum, int* __restrict__ done,
        float* __restrict__ out) {
    __shared__ float sp[4];
    int wave = threadIdx.x >> 6;
    int lane = threadIdx.x & 63;
    int i = blockIdx.x * 4 + wave;
    int deg = deg_arr[i];
    int j0 = (lane < deg)      ? nbr_c[i * MAXDEG + lane]      : 0;
    int j1 = (lane + 64 < deg) ? nbr_c[i * MAXDEG + lane + 64] : 0;
    float hv = agg_core(j0, j1, deg, sdin[i], ssin, hwin, b, lane);
    float v  = x[i * 64 + lane] + hv;
    float mu = wave_reduce_sum(v) * (1.f / 64.f);
    float d  = v - mu;
    float var = wave_reduce_sum(d * d) * (1.f / 64.f);
    float ln  = d * rsqrtf(var + LN_EPS);
    float part = wave_reduce_sum(ln * vw[lane]);
    if (lane == 0) sp[wave] = part;
    __syncthreads();
    if (threadIdx.x == 0) {
        float bp = sp[0] + sp[1] + sp[2] + sp[3];
        atomicAdd(accum, bp);
        __threadfence();
        int old = atomicAdd(done, 1);
        if (old == (N / 4) - 1) {
            float t = __hip_atomic_load(accum, __ATOMIC_RELAXED,
                                        __HIP_MEMORY_SCOPE_AGENT);
            out[0] = fmaxf(t * (1.f / (float)N) + vb[0], 0.f);
        }
    }
}

extern "C" void kernel_launch(void* const* d_in, const int* in_sizes, int n_in,
                              void* d_out, int out_size, void* d_ws, size_t ws_size,
                              hipStream_t stream) {
    const vfloat4* adj4     = (const vfloat4*)d_in[0];
    const int*   timestep   = (const int*)  d_in[1];
    const float* arrivals   = (const float*)d_in[2];
    const float* departures = (const float*)d_in[3];
    const float* hard       = (const float*)d_in[4];
    // d_in[5] active_agents: unused by reference
    const float* emb_w1     = (const float*)d_in[6];
    const float* emb_b1     = (const float*)d_in[7];
    const float* emb_w2     = (const float*)d_in[8];
    const float* emb_b2     = (const float*)d_in[9];
    const float* gat_w      = (const float*)d_in[10];
    const float* gat_asrc   = (const float*)d_in[11];
    const float* gat_adst   = (const float*)d_in[12];
    const float* gat_b      = (const float*)d_in[13];
    const float* val_w      = (const float*)d_in[14];
    const float* val_b      = (const float*)d_in[15];

    const size_t MB = 1u << 20;
    char* ws = (char*)d_ws;
    unsigned short* nbr2 = (unsigned short*)(ws);           // 8 MB (128*4096*8 u16)
    unsigned char*  cnt2 = (unsigned char*) (ws + 8 * MB);  // 512 KB
    int*   nbr_c   = (int*)  (ws + 9 * MB);        // 2 MB
    int*   deg_arr = (int*)  (ws + 11 * MB);       // 16 KB
    float* x       = (float*)(ws + 12 * MB);       // 1 MB
    float* hwA     = (float*)(ws + 13 * MB);       // 1 MB
    float* hwB     = (float*)(ws + 14 * MB);       // 1 MB
    float* ssA     = (float*)(ws + 15 * MB);
    float* sdA     = (float*)(ws + 15 * MB + 65536);
    float* ssB     = (float*)(ws + 15 * MB + 131072);
    float* sdB     = (float*)(ws + 15 * MB + 196608);
    float* accum   = (float*)(ws + 16 * MB);
    int*   done    = (int*)  (ws + 16 * MB + 64);

    prep_kernel<<<1536, 256, 0, stream>>>(adj4, timestep, arrivals, departures, hard,
                                          emb_w1, emb_b1, emb_w2, emb_b2,
                                          gat_w, gat_asrc, gat_adst,
                                          nbr2, cnt2, x, hwA, ssA, sdA, accum, done);
    compact_agg_tr<<<N / 4, 256, 0, stream>>>(nbr2, cnt2, hwA, ssA, sdA, gat_b,
                                              gat_w + 64 * 64, gat_asrc + 64,
                                              gat_adst + 64,
                                              nbr_c, deg_arr, hwB, ssB, sdB);
    agg_tr<<<N / 4, 256, 0, stream>>>(hwB, ssB, sdB, nbr_c, deg_arr, gat_b + 64,
                                      gat_w + 2 * 64 * 64, gat_asrc + 128,
                                      gat_adst + 128, hwA, ssA, sdA);
    agg_final_finish<<<N / 4, 256, 0, stream>>>(hwA, ssA, sdA, nbr_c, deg_arr,
                                                gat_b + 128, x, val_w, val_b,
                                                accum, done, (float*)d_out);
    (void)in_sizes; (void)n_in; (void)out_size; (void)ws_size;
}

// Round 15
// 195.345 us; speedup vs baseline: 1.0258x; 1.0258x over previous
//
#include <hip/hip_runtime.h>
#include <math.h>

#define N 4096
#define NB 128         // bands per column
#define BANDSZ 32      // rows per band
#define KB 8           // slots per (band, col) cell
#define MAXDEG 128
#define NEG_SLOPE 0.2f
#define LN_EPS 1e-5f

typedef float vfloat4 __attribute__((ext_vector_type(4)));  // native vec for nontemporal builtin

__device__ __forceinline__ float wave_reduce_sum(float v) {
    #pragma unroll
    for (int m = 32; m >= 1; m >>= 1) v += __shfl_xor(v, m, 64);
    return v;
}
__device__ __forceinline__ float wave_reduce_max(float v) {
    #pragma unroll
    for (int m = 32; m >= 1; m >>= 1) v = fmaxf(v, __shfl_xor(v, m, 64));
    return v;
}

// row-vector (lane=col) times 64x64 row-major W via shfl broadcast.
__device__ __forceinline__ float transform_row(float hv, const float* __restrict__ W,
                                               int lane) {
    float tr = 0.f;
    #pragma unroll
    for (int k = 0; k < 64; ++k)
        tr += __shfl(hv, k, 64) * W[k * 64 + lane];
    return tr;
}

// softmax over neighbors (j0: first 64, j1: next 64, deg total) + weighted
// aggregation of hwin rows + bias. Indices/probs broadcast via shfl.
__device__ __forceinline__ float agg_core(int j0, int j1, int deg, float sd,
        const float* __restrict__ ssin, const float* __restrict__ hwin,
        const float* __restrict__ b, int lane) {
    float e0 = -1e30f, e1 = -1e30f;
    if (lane < deg)      { float v = ssin[j0] + sd; e0 = v > 0.f ? v : NEG_SLOPE * v; }
    if (lane + 64 < deg) { float v = ssin[j1] + sd; e1 = v > 0.f ? v : NEG_SLOPE * v; }
    float m = wave_reduce_max(fmaxf(e0, e1));
    float p0 = (lane < deg)      ? expf(e0 - m) : 0.f;
    float p1 = (lane + 64 < deg) ? expf(e1 - m) : 0.f;
    float Z = wave_reduce_sum(p0 + p1);
    float acc = 0.f;
    int d0 = min(deg, 64);
    #pragma unroll 4
    for (int n = 0; n < d0; ++n) {
        int   jj = __shfl(j0, n, 64);
        float p  = __shfl(p0, n, 64);
        acc += p * hwin[jj * 64 + lane];
    }
    for (int n = 64; n < deg; ++n) {
        int   jj = __shfl(j1, n - 64, 64);
        float p  = __shfl(p1, n - 64, 64);
        acc += p * hwin[jj * 64 + lane];
    }
    return acc / Z + b[lane];
}

// ---- dispatch 1: banded neighbor build + emb MLP + layer-0 transform.
// R12 geometry + transposed (band*N+col) cell layout (best so far).
// NT loads ONLY for the 64 MB adjacency stream (zero reuse — keep it out
// of L2 so nbr2/cnt2 dirty lines survive to full-line writeback).
// NORMAL stores (R14 lesson: nt scatter-stores of 2B stream partial lines
// to HBM with no coalescing window — 189→200 µs regression).
// Blocks [0,512): build — thread owns 4 consecutive cols x one 32-row band.
// Blocks [512,1536): emb+tr0, one row per wave (keeps VGPR low — R8 lesson).
__global__ void __launch_bounds__(256) prep_kernel(
        const vfloat4* __restrict__ adj4, const int* __restrict__ timestep,
        const float* __restrict__ arr, const float* __restrict__ dep,
        const float* __restrict__ hard,
        const float* __restrict__ w1, const float* __restrict__ b1,
        const float* __restrict__ w2, const float* __restrict__ b2,
        const float* __restrict__ W0, const float* __restrict__ asrc,
        const float* __restrict__ adst,
        unsigned short* __restrict__ nbr2, unsigned char* __restrict__ cnt2,
        float* __restrict__ x, float* __restrict__ hwA,
        float* __restrict__ ssA, float* __restrict__ sdA,
        float* __restrict__ accum, int* __restrict__ done) {
    int wave = threadIdx.x >> 6;
    int lane = threadIdx.x & 63;
    if (blockIdx.x < 512) {
        int t    = blockIdx.x * 256 + threadIdx.x;   // 0..131071
        int cg   = t & 1023;                          // col group (4 cols)
        int band = t >> 10;                           // 0..127
        int i0   = cg * 4;
        int jbase = band * BANDSZ;
        int lc0 = 0, lc1 = 0, lc2 = 0, lc3 = 0;
        int b0  = (band * N + i0) * KB;               // 4 cells = one 64B line
        int b1  = b0 + KB;
        int b2_ = b0 + 2 * KB;
        int b3  = b0 + 3 * KB;
        #pragma unroll
        for (int batch = 0; batch < 4; ++batch) {
            vfloat4 a[8];
            #pragma unroll
            for (int u = 0; u < 8; ++u)
                a[u] = __builtin_nontemporal_load(
                           &adj4[(size_t)(jbase + batch * 8 + u) * 1024 + cg]);
            #pragma unroll
            for (int u = 0; u < 8; ++u) {
                int j = jbase + batch * 8 + u;
                if (a[u].x != 0.f || j == i0)     { if (lc0 < KB) nbr2[b0  + lc0] = (unsigned short)j; ++lc0; }
                if (a[u].y != 0.f || j == i0 + 1) { if (lc1 < KB) nbr2[b1  + lc1] = (unsigned short)j; ++lc1; }
                if (a[u].z != 0.f || j == i0 + 2) { if (lc2 < KB) nbr2[b2_ + lc2] = (unsigned short)j; ++lc2; }
                if (a[u].w != 0.f || j == i0 + 3) { if (lc3 < KB) nbr2[b3  + lc3] = (unsigned short)j; ++lc3; }
            }
        }
        int cb = band * N + i0;                       // 4 consecutive u8
        cnt2[cb]     = (unsigned char)(lc0 < KB ? lc0 : KB);
        cnt2[cb + 1] = (unsigned char)(lc1 < KB ? lc1 : KB);
        cnt2[cb + 2] = (unsigned char)(lc2 < KB ? lc2 : KB);
        cnt2[cb + 3] = (unsigned char)(lc3 < KB ? lc3 : KB);
        if (blockIdx.x == 0 && threadIdx.x == 0) { *accum = 0.f; *done = 0; }
    } else {
        int row = (blockIdx.x - 512) * 4 + wave;      // one row per wave
        float ts = (float)(*timestep);
        float pr = (ts - arr[row]) / (dep[row] - arr[row]);
        float hd = hard[row];
        float t  = pr * w1[lane] + hd * w1[64 + lane] + b1[lane];
        float xv = b2[lane];
        #pragma unroll
        for (int k = 0; k < 64; ++k)
            xv += __shfl(t, k, 64) * w2[k * 64 + lane];
        x[row * 64 + lane] = xv;
        float tr = transform_row(xv, W0, lane);
        hwA[row * 64 + lane] = tr;
        float s1 = wave_reduce_sum(tr * asrc[lane]);
        float s2 = wave_reduce_sum(tr * adst[lane]);
        if (lane == 0) { ssA[row] = s1; sdA[row] = s2; }
    }
}

// ---- dispatch 2: compact banded lists (lane owns 2 bands of its row; wave
// prefix scan) + layer-0 aggregate + relu + layer-1 transform + scores.
__global__ void __launch_bounds__(256) compact_agg_tr(
        const unsigned short* __restrict__ nbr2, const unsigned char* __restrict__ cnt2,
        const float* __restrict__ hwin, const float* __restrict__ ssin,
        const float* __restrict__ sdin, const float* __restrict__ b,
        const float* __restrict__ W, const float* __restrict__ asrc,
        const float* __restrict__ adst,
        int* __restrict__ nbr_c, int* __restrict__ deg_arr,
        float* __restrict__ hwout, float* __restrict__ ssout,
        float* __restrict__ sdout) {
    __shared__ int lds[4][MAXDEG];
    int wave = threadIdx.x >> 6;
    int lane = threadIdx.x & 63;
    int i = blockIdx.x * 4 + wave;
    int cell0 = (2 * lane)     * N + i;   // transposed layout: band*N + col
    int cell1 = (2 * lane + 1) * N + i;
    int c0 = min((int)cnt2[cell0], KB);
    int c1 = min((int)cnt2[cell1], KB);
    int c  = c0 + c1;
    int inc = c;
    #pragma unroll
    for (int s = 1; s < 64; s <<= 1) {
        int t = __shfl_up(inc, s, 64);
        if (lane >= s) inc += t;
    }
    int off = inc - c;
    int deg = min(__shfl(inc, 63, 64), MAXDEG);
    {
        int base0 = cell0 * KB;
        int o = off;
        for (int k = 0; k < c0; ++k) { if (o < MAXDEG) lds[wave][o] = (int)nbr2[base0 + k]; ++o; }
        int base1 = cell1 * KB;
        for (int k = 0; k < c1; ++k) { if (o < MAXDEG) lds[wave][o] = (int)nbr2[base1 + k]; ++o; }
    }
    __syncthreads();
    int j0 = (lane < deg)      ? lds[wave][lane]      : 0;
    int j1 = (lane + 64 < deg) ? lds[wave][lane + 64] : 0;
    if (lane < deg)      nbr_c[i * MAXDEG + lane]      = j0;
    if (lane + 64 < deg) nbr_c[i * MAXDEG + lane + 64] = j1;
    if (lane == 0) deg_arr[i] = deg;
    float hv = fmaxf(agg_core(j0, j1, deg, sdin[i], ssin, hwin, b, lane), 0.f);
    float tr = transform_row(hv, W, lane);
    hwout[i * 64 + lane] = tr;
    float s1 = wave_reduce_sum(tr * asrc[lane]);
    float s2 = wave_reduce_sum(tr * adst[lane]);
    if (lane == 0) { ssout[i] = s1; sdout[i] = s2; }
}

// ---- dispatch 3: layer-1 aggregate + relu + layer-2 transform + scores.
__global__ void __launch_bounds__(256) agg_tr(
        const float* __restrict__ hwin, const float* __restrict__ ssin,
        const float* __restrict__ sdin, const int* __restrict__ nbr_c,
        const int* __restrict__ deg_arr, const float* __restrict__ b,
        const float* __restrict__ W, const float* __restrict__ asrc,
        const float* __restrict__ adst,
        float* __restrict__ hwout, float* __restrict__ ssout,
        float* __restrict__ sdout) {
    int wave = threadIdx.x >> 6;
    int lane = threadIdx.x & 63;
    int i = blockIdx.x * 4 + wave;
    int deg = deg_arr[i];
    int j0 = (lane < deg)      ? nbr_c[i * MAXDEG + lane]      : 0;
    int j1 = (lane + 64 < deg) ? nbr_c[i * MAXDEG + lane + 64] : 0;
    float hv = fmaxf(agg_core(j0, j1, deg, sdin[i], ssin, hwin, b, lane), 0.f);
    float tr = transform_row(hv, W, lane);
    hwout[i * 64 + lane] = tr;
    float s1 = wave_reduce_sum(tr * asrc[lane]);
    float s2 = wave_reduce_sum(tr * adst[lane]);
    if (lane == 0) { ssout[i] = s1; sdout[i] = s2; }
}

// ---- dispatch 4: layer-2 aggregate + residual + layernorm + val_w dot +
// block atomicAdd + last-block finish (accum/done pre-zeroed by dispatch 1).
__global__ void __launch_bounds__(256) agg_final_finish(
        const float* __restrict__ hwin, const float* __restrict__ ssin,
        const float* __restrict__ sdin, const int* __restrict__ nbr_c,
        const int* __restrict__ deg_arr, const float* __restrict__ b,
        const float* __restrict__ x, const float* __restrict__ vw,
        const float* __restrict__ vb,
        float* __restrict__ accum, int* __restrict__ done,
        float* __restrict__ out) {
    __shared__ float sp[4];
    int wave = threadIdx.x >> 6;
    int lane = threadIdx.x & 63;
    int i = blockIdx.x * 4 + wave;
    int deg = deg_arr[i];
    int j0 = (lane < deg)      ? nbr_c[i * MAXDEG + lane]      : 0;
    int j1 = (lane + 64 < deg) ? nbr_c[i * MAXDEG + lane + 64] : 0;
    float hv = agg_core(j0, j1, deg, sdin[i], ssin, hwin, b, lane);
    float v  = x[i * 64 + lane] + hv;
    float mu = wave_reduce_sum(v) * (1.f / 64.f);
    float d  = v - mu;
    float var = wave_reduce_sum(d * d) * (1.f / 64.f);
    float ln  = d * rsqrtf(var + LN_EPS);
    float part = wave_reduce_sum(ln * vw[lane]);
    if (lane == 0) sp[wave] = part;
    __syncthreads();
    if (threadIdx.x == 0) {
        float bp = sp[0] + sp[1] + sp[2] + sp[3];
        atomicAdd(accum, bp);
        __threadfence();
        int old = atomicAdd(done, 1);
        if (old == (N / 4) - 1) {
            float t = __hip_atomic_load(accum, __ATOMIC_RELAXED,
                                        __HIP_MEMORY_SCOPE_AGENT);
            out[0] = fmaxf(t * (1.f / (float)N) + vb[0], 0.f);
        }
    }
}

extern "C" void kernel_launch(void* const* d_in, const int* in_sizes, int n_in,
                              void* d_out, int out_size, void* d_ws, size_t ws_size,
                              hipStream_t stream) {
    const vfloat4* adj4     = (const vfloat4*)d_in[0];
    const int*   timestep   = (const int*)  d_in[1];
    const float* arrivals   = (const float*)d_in[2];
    const float* departures = (const float*)d_in[3];
    const float* hard       = (const float*)d_in[4];
    // d_in[5] active_agents: unused by reference
    const float* emb_w1     = (const float*)d_in[6];
    const float* emb_b1     = (const float*)d_in[7];
    const float* emb_w2     = (const float*)d_in[8];
    const float* emb_b2     = (const float*)d_in[9];
    const float* gat_w      = (const float*)d_in[10];
    const float* gat_asrc   = (const float*)d_in[11];
    const float* gat_adst   = (const float*)d_in[12];
    const float* gat_b      = (const float*)d_in[13];
    const float* val_w      = (const float*)d_in[14];
    const float* val_b      = (const float*)d_in[15];

    const size_t MB = 1u << 20;
    char* ws = (char*)d_ws;
    unsigned short* nbr2 = (unsigned short*)(ws);           // 8 MB (128*4096*8 u16)
    unsigned char*  cnt2 = (unsigned char*) (ws + 8 * MB);  // 512 KB
    int*   nbr_c   = (int*)  (ws + 9 * MB);        // 2 MB
    int*   deg_arr = (int*)  (ws + 11 * MB);       // 16 KB
    float* x       = (float*)(ws + 12 * MB);       // 1 MB
    float* hwA     = (float*)(ws + 13 * MB);       // 1 MB
    float* hwB     = (float*)(ws + 14 * MB);       // 1 MB
    float* ssA     = (float*)(ws + 15 * MB);
    float* sdA     = (float*)(ws + 15 * MB + 65536);
    float* ssB     = (float*)(ws + 15 * MB + 131072);
    float* sdB     = (float*)(ws + 15 * MB + 196608);
    float* accum   = (float*)(ws + 16 * MB);
    int*   done    = (int*)  (ws + 16 * MB + 64);

    prep_kernel<<<1536, 256, 0, stream>>>(adj4, timestep, arrivals, departures, hard,
                                          emb_w1, emb_b1, emb_w2, emb_b2,
                                          gat_w, gat_asrc, gat_adst,
                                          nbr2, cnt2, x, hwA, ssA, sdA, accum, done);
    compact_agg_tr<<<N / 4, 256, 0, stream>>>(nbr2, cnt2, hwA, ssA, sdA, gat_b,
                                              gat_w + 64 * 64, gat_asrc + 64,
                                              gat_adst + 64,
                                              nbr_c, deg_arr, hwB, ssB, sdB);
    agg_tr<<<N / 4, 256, 0, stream>>>(hwB, ssB, sdB, nbr_c, deg_arr, gat_b + 64,
                                      gat_w + 2 * 64 * 64, gat_asrc + 128,
                                      gat_adst + 128, hwA, ssA, sdA);
    agg_final_finish<<<N / 4, 256, 0, stream>>>(hwA, ssA, sdA, nbr_c, deg_arr,
                                                gat_b + 128, x, val_w, val_b,
                                                accum, done, (float*)d_out);
    (void)in_sizes; (void)n_in; (void)out_size; (void)ws_size;
}

// Round 16
// 189.005 us; speedup vs baseline: 1.0602x; 1.0335x over previous
//
#include <hip/hip_runtime.h>
#include <math.h>

#define N 4096
#define NB 128         // bands per column
#define BANDSZ 32      // rows per band
#define KB 8           // slots per (band, col) cell
#define MAXDEG 128
#define NEG_SLOPE 0.2f
#define LN_EPS 1e-5f

__device__ __forceinline__ float wave_reduce_sum(float v) {
    #pragma unroll
    for (int m = 32; m >= 1; m >>= 1) v += __shfl_xor(v, m, 64);
    return v;
}
__device__ __forceinline__ float wave_reduce_max(float v) {
    #pragma unroll
    for (int m = 32; m >= 1; m >>= 1) v = fmaxf(v, __shfl_xor(v, m, 64));
    return v;
}

// row-vector (lane=col) times 64x64 row-major W via shfl broadcast.
__device__ __forceinline__ float transform_row(float hv, const float* __restrict__ W,
                                               int lane) {
    float tr = 0.f;
    #pragma unroll
    for (int k = 0; k < 64; ++k)
        tr += __shfl(hv, k, 64) * W[k * 64 + lane];
    return tr;
}

// softmax over neighbors (j0: first 64, j1: next 64, deg total) + weighted
// aggregation of hwin rows + bias. Indices/probs broadcast via shfl.
__device__ __forceinline__ float agg_core(int j0, int j1, int deg, float sd,
        const float* __restrict__ ssin, const float* __restrict__ hwin,
        const float* __restrict__ b, int lane) {
    float e0 = -1e30f, e1 = -1e30f;
    if (lane < deg)      { float v = ssin[j0] + sd; e0 = v > 0.f ? v : NEG_SLOPE * v; }
    if (lane + 64 < deg) { float v = ssin[j1] + sd; e1 = v > 0.f ? v : NEG_SLOPE * v; }
    float m = wave_reduce_max(fmaxf(e0, e1));
    float p0 = (lane < deg)      ? expf(e0 - m) : 0.f;
    float p1 = (lane + 64 < deg) ? expf(e1 - m) : 0.f;
    float Z = wave_reduce_sum(p0 + p1);
    float acc = 0.f;
    int d0 = min(deg, 64);
    #pragma unroll 4
    for (int n = 0; n < d0; ++n) {
        int   jj = __shfl(j0, n, 64);
        float p  = __shfl(p0, n, 64);
        acc += p * hwin[jj * 64 + lane];
    }
    for (int n = 64; n < deg; ++n) {
        int   jj = __shfl(j1, n - 64, 64);
        float p  = __shfl(p1, n - 64, 64);
        acc += p * hwin[jj * 64 + lane];
    }
    return acc / Z + b[lane];
}

// ---- dispatch 1: banded neighbor build (atomic-free, batched float4 loads)
// + emb MLP + layer-0 transform.  Measured-optimal configuration (R12,
// 189.4 µs): 512 build blocks, thread owns 4 consecutive cols x one 32-row
// band, 4 batches x 8 unconditional float4 loads; cells in transposed
// (band*N + col) layout so a thread's 4 cells = one private 64B line
// (no cross-XCD false sharing); u16 slots + u8 counts halve write surface.
// NORMAL loads/stores — nontemporal regressed both ways (R14: nt stores
// −11 µs; R15: nt loads −6 µs).
// Blocks [512,1536): emb+tr0, one row per wave (keeps VGPR low — R8 lesson).
__global__ void __launch_bounds__(256) prep_kernel(
        const float4* __restrict__ adj4, const int* __restrict__ timestep,
        const float* __restrict__ arr, const float* __restrict__ dep,
        const float* __restrict__ hard,
        const float* __restrict__ w1, const float* __restrict__ b1,
        const float* __restrict__ w2, const float* __restrict__ b2,
        const float* __restrict__ W0, const float* __restrict__ asrc,
        const float* __restrict__ adst,
        unsigned short* __restrict__ nbr2, unsigned char* __restrict__ cnt2,
        float* __restrict__ x, float* __restrict__ hwA,
        float* __restrict__ ssA, float* __restrict__ sdA,
        float* __restrict__ accum, int* __restrict__ done) {
    int wave = threadIdx.x >> 6;
    int lane = threadIdx.x & 63;
    if (blockIdx.x < 512) {
        int t    = blockIdx.x * 256 + threadIdx.x;   // 0..131071
        int cg   = t & 1023;                          // col group (4 cols)
        int band = t >> 10;                           // 0..127
        int i0   = cg * 4;
        int jbase = band * BANDSZ;
        int lc0 = 0, lc1 = 0, lc2 = 0, lc3 = 0;
        int b0  = (band * N + i0) * KB;               // 4 cells = one 64B line
        int b1  = b0 + KB;
        int b2_ = b0 + 2 * KB;
        int b3  = b0 + 3 * KB;
        #pragma unroll
        for (int batch = 0; batch < 4; ++batch) {
            float4 a[8];
            #pragma unroll
            for (int u = 0; u < 8; ++u)
                a[u] = adj4[(size_t)(jbase + batch * 8 + u) * 1024 + cg];
            #pragma unroll
            for (int u = 0; u < 8; ++u) {
                int j = jbase + batch * 8 + u;
                if (a[u].x != 0.f || j == i0)     { if (lc0 < KB) nbr2[b0  + lc0] = (unsigned short)j; ++lc0; }
                if (a[u].y != 0.f || j == i0 + 1) { if (lc1 < KB) nbr2[b1  + lc1] = (unsigned short)j; ++lc1; }
                if (a[u].z != 0.f || j == i0 + 2) { if (lc2 < KB) nbr2[b2_ + lc2] = (unsigned short)j; ++lc2; }
                if (a[u].w != 0.f || j == i0 + 3) { if (lc3 < KB) nbr2[b3  + lc3] = (unsigned short)j; ++lc3; }
            }
        }
        int cb = band * N + i0;                       // 4 consecutive u8
        cnt2[cb]     = (unsigned char)(lc0 < KB ? lc0 : KB);
        cnt2[cb + 1] = (unsigned char)(lc1 < KB ? lc1 : KB);
        cnt2[cb + 2] = (unsigned char)(lc2 < KB ? lc2 : KB);
        cnt2[cb + 3] = (unsigned char)(lc3 < KB ? lc3 : KB);
        if (blockIdx.x == 0 && threadIdx.x == 0) { *accum = 0.f; *done = 0; }
    } else {
        int row = (blockIdx.x - 512) * 4 + wave;      // one row per wave
        float ts = (float)(*timestep);
        float pr = (ts - arr[row]) / (dep[row] - arr[row]);
        float hd = hard[row];
        float t  = pr * w1[lane] + hd * w1[64 + lane] + b1[lane];
        float xv = b2[lane];
        #pragma unroll
        for (int k = 0; k < 64; ++k)
            xv += __shfl(t, k, 64) * w2[k * 64 + lane];
        x[row * 64 + lane] = xv;
        float tr = transform_row(xv, W0, lane);
        hwA[row * 64 + lane] = tr;
        float s1 = wave_reduce_sum(tr * asrc[lane]);
        float s2 = wave_reduce_sum(tr * adst[lane]);
        if (lane == 0) { ssA[row] = s1; sdA[row] = s2; }
    }
}

// ---- dispatch 2: compact banded lists (lane owns 2 bands of its row; wave
// prefix scan) + layer-0 aggregate + relu + layer-1 transform + scores.
__global__ void __launch_bounds__(256) compact_agg_tr(
        const unsigned short* __restrict__ nbr2, const unsigned char* __restrict__ cnt2,
        const float* __restrict__ hwin, const float* __restrict__ ssin,
        const float* __restrict__ sdin, const float* __restrict__ b,
        const float* __restrict__ W, const float* __restrict__ asrc,
        const float* __restrict__ adst,
        int* __restrict__ nbr_c, int* __restrict__ deg_arr,
        float* __restrict__ hwout, float* __restrict__ ssout,
        float* __restrict__ sdout) {
    __shared__ int lds[4][MAXDEG];
    int wave = threadIdx.x >> 6;
    int lane = threadIdx.x & 63;
    int i = blockIdx.x * 4 + wave;
    int cell0 = (2 * lane)     * N + i;   // transposed layout: band*N + col
    int cell1 = (2 * lane + 1) * N + i;
    int c0 = min((int)cnt2[cell0], KB);
    int c1 = min((int)cnt2[cell1], KB);
    int c  = c0 + c1;
    int inc = c;
    #pragma unroll
    for (int s = 1; s < 64; s <<= 1) {
        int t = __shfl_up(inc, s, 64);
        if (lane >= s) inc += t;
    }
    int off = inc - c;
    int deg = min(__shfl(inc, 63, 64), MAXDEG);
    {
        int base0 = cell0 * KB;
        int o = off;
        for (int k = 0; k < c0; ++k) { if (o < MAXDEG) lds[wave][o] = (int)nbr2[base0 + k]; ++o; }
        int base1 = cell1 * KB;
        for (int k = 0; k < c1; ++k) { if (o < MAXDEG) lds[wave][o] = (int)nbr2[base1 + k]; ++o; }
    }
    __syncthreads();
    int j0 = (lane < deg)      ? lds[wave][lane]      : 0;
    int j1 = (lane + 64 < deg) ? lds[wave][lane + 64] : 0;
    if (lane < deg)      nbr_c[i * MAXDEG + lane]      = j0;
    if (lane + 64 < deg) nbr_c[i * MAXDEG + lane + 64] = j1;
    if (lane == 0) deg_arr[i] = deg;
    float hv = fmaxf(agg_core(j0, j1, deg, sdin[i], ssin, hwin, b, lane), 0.f);
    float tr = transform_row(hv, W, lane);
    hwout[i * 64 + lane] = tr;
    float s1 = wave_reduce_sum(tr * asrc[lane]);
    float s2 = wave_reduce_sum(tr * adst[lane]);
    if (lane == 0) { ssout[i] = s1; sdout[i] = s2; }
}

// ---- dispatch 3: layer-1 aggregate + relu + layer-2 transform + scores.
__global__ void __launch_bounds__(256) agg_tr(
        const float* __restrict__ hwin, const float* __restrict__ ssin,
        const float* __restrict__ sdin, const int* __restrict__ nbr_c,
        const int* __restrict__ deg_arr, const float* __restrict__ b,
        const float* __restrict__ W, const float* __restrict__ asrc,
        const float* __restrict__ adst,
        float* __restrict__ hwout, float* __restrict__ ssout,
        float* __restrict__ sdout) {
    int wave = threadIdx.x >> 6;
    int lane = threadIdx.x & 63;
    int i = blockIdx.x * 4 + wave;
    int deg = deg_arr[i];
    int j0 = (lane < deg)      ? nbr_c[i * MAXDEG + lane]      : 0;
    int j1 = (lane + 64 < deg) ? nbr_c[i * MAXDEG + lane + 64] : 0;
    float hv = fmaxf(agg_core(j0, j1, deg, sdin[i], ssin, hwin, b, lane), 0.f);
    float tr = transform_row(hv, W, lane);
    hwout[i * 64 + lane] = tr;
    float s1 = wave_reduce_sum(tr * asrc[lane]);
    float s2 = wave_reduce_sum(tr * adst[lane]);
    if (lane == 0) { ssout[i] = s1; sdout[i] = s2; }
}

// ---- dispatch 4: layer-2 aggregate + residual + layernorm + val_w dot +
// block atomicAdd + last-block finish (accum/done pre-zeroed by dispatch 1).
__global__ void __launch_bounds__(256) agg_final_finish(
        const float* __restrict__ hwin, const float* __restrict__ ssin,
        const float* __restrict__ sdin, const int* __restrict__ nbr_c,
        const int* __restrict__ deg_arr, const float* __restrict__ b,
        const float* __restrict__ x, const float* __restrict__ vw,
        const float* __restrict__ vb,
        float* __restrict__ accum, int* __restrict__ done,
        float* __restrict__ out) {
    __shared__ float sp[4];
    int wave = threadIdx.x >> 6;
    int lane = threadIdx.x & 63;
    int i = blockIdx.x * 4 + wave;
    int deg = deg_arr[i];
    int j0 = (lane < deg)      ? nbr_c[i * MAXDEG + lane]      : 0;
    int j1 = (lane + 64 < deg) ? nbr_c[i * MAXDEG + lane + 64] : 0;
    float hv = agg_core(j0, j1, deg, sdin[i], ssin, hwin, b, lane);
    float v  = x[i * 64 + lane] + hv;
    float mu = wave_reduce_sum(v) * (1.f / 64.f);
    float d  = v - mu;
    float var = wave_reduce_sum(d * d) * (1.f / 64.f);
    float ln  = d * rsqrtf(var + LN_EPS);
    float part = wave_reduce_sum(ln * vw[lane]);
    if (lane == 0) sp[wave] = part;
    __syncthreads();
    if (threadIdx.x == 0) {
        float bp = sp[0] + sp[1] + sp[2] + sp[3];
        atomicAdd(accum, bp);
        __threadfence();
        int old = atomicAdd(done, 1);
        if (old == (N / 4) - 1) {
            float t = __hip_atomic_load(accum, __ATOMIC_RELAXED,
                                        __HIP_MEMORY_SCOPE_AGENT);
            out[0] = fmaxf(t * (1.f / (float)N) + vb[0], 0.f);
        }
    }
}

extern "C" void kernel_launch(void* const* d_in, const int* in_sizes, int n_in,
                              void* d_out, int out_size, void* d_ws, size_t ws_size,
                              hipStream_t stream) {
    const float4* adj4      = (const float4*)d_in[0];
    const int*   timestep   = (const int*)  d_in[1];
    const float* arrivals   = (const float*)d_in[2];
    const float* departures = (const float*)d_in[3];
    const float* hard       = (const float*)d_in[4];
    // d_in[5] active_agents: unused by reference
    const float* emb_w1     = (const float*)d_in[6];
    const float* emb_b1     = (const float*)d_in[7];
    const float* emb_w2     = (const float*)d_in[8];
    const float* emb_b2     = (const float*)d_in[9];
    const float* gat_w      = (const float*)d_in[10];
    const float* gat_asrc   = (const float*)d_in[11];
    const float* gat_adst   = (const float*)d_in[12];
    const float* gat_b      = (const float*)d_in[13];
    const float* val_w      = (const float*)d_in[14];
    const float* val_b      = (const float*)d_in[15];

    const size_t MB = 1u << 20;
    char* ws = (char*)d_ws;
    unsigned short* nbr2 = (unsigned short*)(ws);           // 8 MB (128*4096*8 u16)
    unsigned char*  cnt2 = (unsigned char*) (ws + 8 * MB);  // 512 KB
    int*   nbr_c   = (int*)  (ws + 9 * MB);        // 2 MB
    int*   deg_arr = (int*)  (ws + 11 * MB);       // 16 KB
    float* x       = (float*)(ws + 12 * MB);       // 1 MB
    float* hwA     = (float*)(ws + 13 * MB);       // 1 MB
    float* hwB     = (float*)(ws + 14 * MB);       // 1 MB
    float* ssA     = (float*)(ws + 15 * MB);
    float* sdA     = (float*)(ws + 15 * MB + 65536);
    float* ssB     = (float*)(ws + 15 * MB + 131072);
    float* sdB     = (float*)(ws + 15 * MB + 196608);
    float* accum   = (float*)(ws + 16 * MB);
    int*   done    = (int*)  (ws + 16 * MB + 64);

    prep_kernel<<<1536, 256, 0, stream>>>(adj4, timestep, arrivals, departures, hard,
                                          emb_w1, emb_b1, emb_w2, emb_b2,
                                          gat_w, gat_asrc, gat_adst,
                                          nbr2, cnt2, x, hwA, ssA, sdA, accum, done);
    compact_agg_tr<<<N / 4, 256, 0, stream>>>(nbr2, cnt2, hwA, ssA, sdA, gat_b,
                                              gat_w + 64 * 64, gat_asrc + 64,
                                              gat_adst + 64,
                                              nbr_c, deg_arr, hwB, ssB, sdB);
    agg_tr<<<N / 4, 256, 0, stream>>>(hwB, ssB, sdB, nbr_c, deg_arr, gat_b + 64,
                                      gat_w + 2 * 64 * 64, gat_asrc + 128,
                                      gat_adst + 128, hwA, ssA, sdA);
    agg_final_finish<<<N / 4, 256, 0, stream>>>(hwA, ssA, sdA, nbr_c, deg_arr,
                                                gat_b + 128, x, val_w, val_b,
                                                accum, done, (float*)d_out);
    (void)in_sizes; (void)n_in; (void)out_size; (void)ws_size;
}